// Round 10
// baseline (184.618 us; speedup 1.0000x reference)
//
#include <hip/hip_runtime.h>
#include <hip/hip_bf16.h>
#include <stdint.h>

#define IN_F 4096
#define OUT_F 11008
#define NUM_CH 128
#define NUM_NORM 3968
#define BATCH 64
#define KSPLIT 16
#define KCHUNK (IN_F / KSPLIT)   // 256 = 2 megasteps = 2 scale groups
#define NMEGA 2
#define BS 136                   // LDS k-stride in shorts (16B-aligned)

typedef short short8 __attribute__((ext_vector_type(8)));
typedef float float4v __attribute__((ext_vector_type(4)));
typedef int int4v __attribute__((ext_vector_type(4)));

// Barrier WITHOUT the implicit s_waitcnt vmcnt(0) of __syncthreads():
// waits only this wave's LDS ops; global loads stay in flight across it.
__device__ __forceinline__ void barrier_no_vmcnt() {
    asm volatile("s_waitcnt lgkmcnt(0)\n\ts_barrier" ::: "memory");
}

__device__ __forceinline__ unsigned short f2bf(float f) {
    union { float f; unsigned u; } v; v.f = f;
    unsigned u = v.u;
    return (unsigned short)((u + 0x7FFFu + ((u >> 16) & 1u)) >> 16);
}

__device__ __forceinline__ unsigned pk_bf16(float lo, float hi) {
    __hip_bfloat162 h = __float22bfloat162_rn(make_float2(lo, hi));  // v_cvt_pk_bf16_f32
    union { __hip_bfloat162 h; unsigned u; } c; c.h = h; return c.u;
}

// Gather-permute x into bf16 xp[64][4096]
__global__ __launch_bounds__(256) void permute_x(
        const float* __restrict__ x, const int* __restrict__ cidx,
        unsigned short* __restrict__ xp) {
    int i = blockIdx.x * blockDim.x + threadIdx.x;
    int b = blockIdx.y;
    int lo = 0, hi = NUM_CH;
    while (lo < hi) { int mid = (lo + hi) >> 1; if (cidx[mid] < i) lo = mid + 1; else hi = mid; }
    bool isch = (lo < NUM_CH) && (cidx[lo] == i);
    int pos = isch ? (NUM_NORM + lo) : (i - lo);
    xp[b * IN_F + pos] = f2bf(x[b * IN_F + i]);
}

// out[m][n] = bias[n] + sum_ky part[ky][m][n]
__global__ __launch_bounds__(256) void reduce_out(
        const float* __restrict__ part, const float* __restrict__ bias,
        float* __restrict__ out) {
    const int i = blockIdx.x * 256 + threadIdx.x;          // float4 index
    const int c = i % (OUT_F / 4);
    float4v s = *reinterpret_cast<const float4v*>(bias + c * 4);
    #pragma unroll
    for (int ky = 0; ky < KSPLIT; ++ky) {
        const float4v p = reinterpret_cast<const float4v*>(
            part + (size_t)ky * BATCH * OUT_F)[i];
        s = (float4v){s[0] + p[0], s[1] + p[1], s[2] + p[2], s[3] + p[3]};
    }
    reinterpret_cast<float4v*>(out)[i] = s;
}

// Fused dequant + bf16 MFMA GEMM, zero in-loop global loads.
// Block: 64n x 64m x 256k. Waves split N (16 n each); A for the WHOLE chunk
// is register-resident (4 m-frags x 8 substeps, loaded in the prologue burst
// together with megastep-0 qweight + both scale groups). K-loop = dequant ->
// LDS -> light barrier -> 4x ds_read_b128 -> 16 MFMA. Two barriers per block
// total, neither drains vmem.
__global__ __launch_bounds__(256, 2) void qgemm(
        const unsigned short* __restrict__ xp, const int* __restrict__ qw,
        const float* __restrict__ cw, const float* __restrict__ scales,
        float* __restrict__ part) {
    __shared__ unsigned short Bt[2][64][BS];   // 2 x 17.4 KB, each used once

    const int tid  = threadIdx.x;
    const int wave = tid >> 6;
    const int lane = tid & 63;
    const int ln   = lane & 15;
    const int lq   = lane >> 4;
    const int n0    = blockIdx.x * 64;
    const int ky    = blockIdx.y;
    const int kbase = ky * KCHUNK;
    const int tcol = (tid & 15) << 2;   // staging col 0..60
    const int trow = tid >> 4;          // staging row group 0..15

    const int*   qbase = qw + n0 + tcol;
    const float* sbase = scales + n0 + tcol;
    const float* cbase = cw + n0 + tcol;

    // ---- PROLOGUE BURST: all global reads for the whole chunk ----
    // A: 4 m-frags x 8 substeps, register-resident (128 VGPRs)
    short8 a_all[4][8];
    #pragma unroll
    for (int mt = 0; mt < 4; ++mt) {
        const unsigned short* ap = xp + (size_t)(mt * 16 + ln) * IN_F + kbase + (lq << 3);
        #pragma unroll
        for (int j = 0; j < 8; ++j)
            a_all[mt][j] = *reinterpret_cast<const short8*>(ap + j * 32);
    }
    // megastep-0 qweight rows (always normal region) + both scale groups
    int4v qc[4];
    {
        const int rb = (kbase >> 1) + 4 * trow;
        #pragma unroll
        for (int i = 0; i < 4; ++i)
            qc[i] = *reinterpret_cast<const int4v*>(qbase + (size_t)(rb + i) * OUT_F);
    }
    float4v sc0 = *reinterpret_cast<const float4v*>(
        sbase + (size_t)(kbase >> 7) * OUT_F);
    float4v sc1 = sc0;
    const bool m1_normal = (kbase + 128 < NUM_NORM);
    if (m1_normal)
        sc1 = *reinterpret_cast<const float4v*>(
            sbase + (size_t)((kbase >> 7) + 1) * OUT_F);

    float4v acc[4];
    #pragma unroll
    for (int s = 0; s < 4; ++s) acc[s] = (float4v){0.f, 0.f, 0.f, 0.f};

    #pragma unroll
    for (int s = 0; s < NMEGA; ++s) {
        const int k0 = kbase + s * 128;
        unsigned short (*buf)[BS] = Bt[s];

        if (s == 0 || m1_normal) {
            const int4v q0 = qc[0], q1 = qc[1], q2 = qc[2], q3 = qc[3];
            const float4v sc = (s == 0) ? sc0 : sc1;
            // prefetch megastep-1 qweight during megastep-0 dequant
            if (s == 0 && m1_normal) {
                const int rb = ((k0 + 128) >> 1) + 4 * trow;
                #pragma unroll
                for (int i = 0; i < 4; ++i)
                    qc[i] = *reinterpret_cast<const int4v*>(qbase + (size_t)(rb + i) * OUT_F);
            }
            const int4v qq[4] = {q0, q1, q2, q3};
            #pragma unroll
            for (int cc = 0; cc < 4; ++cc) {
                union { short8 v; unsigned u[4]; } wv;
                const float s1 = sc[cc];
                #pragma unroll
                for (int i = 0; i < 4; ++i) {
                    const int q = qq[i][cc];
                    wv.u[i] = pk_bf16((float)((q & 0xF) - 8) * s1,
                                      (float)(((q >> 4) & 0xF) - 8) * s1);
                }
                *reinterpret_cast<short8*>(&buf[tcol + cc][trow * 8]) = wv.v;
            }
        } else {
            // cherry megastep (only ky==15, s==1): inline loads, 172 blocks only
            float4v ch[8];
            #pragma unroll
            for (int j = 0; j < 8; ++j)
                ch[j] = *reinterpret_cast<const float4v*>(
                    cbase + (size_t)(8 * trow + j) * OUT_F);
            #pragma unroll
            for (int cc = 0; cc < 4; ++cc) {
                union { short8 v; unsigned u[4]; } wv;
                #pragma unroll
                for (int m = 0; m < 4; ++m)
                    wv.u[m] = pk_bf16(ch[2 * m][cc], ch[2 * m + 1][cc]);
                *reinterpret_cast<short8*>(&buf[tcol + cc][trow * 8]) = wv.v;
            }
        }

        barrier_no_vmcnt();   // orders LDS write->read; vmem stays in flight

        // wave's private 16-n window; 4 substeps x 4 m-frags, A from registers
        const unsigned short* brow = &buf[(wave << 4) + ln][lq << 3];
        const short8 b0 = *reinterpret_cast<const short8*>(brow);
        const short8 b1 = *reinterpret_cast<const short8*>(brow + 32);
        const short8 b2 = *reinterpret_cast<const short8*>(brow + 64);
        const short8 b3 = *reinterpret_cast<const short8*>(brow + 96);

        #pragma unroll
        for (int mt = 0; mt < 4; ++mt) {
            acc[mt] = __builtin_amdgcn_mfma_f32_16x16x32_bf16(a_all[mt][s * 4 + 0], b0, acc[mt], 0, 0, 0);
            acc[mt] = __builtin_amdgcn_mfma_f32_16x16x32_bf16(a_all[mt][s * 4 + 1], b1, acc[mt], 0, 0, 0);
            acc[mt] = __builtin_amdgcn_mfma_f32_16x16x32_bf16(a_all[mt][s * 4 + 2], b2, acc[mt], 0, 0, 0);
            acc[mt] = __builtin_amdgcn_mfma_f32_16x16x32_bf16(a_all[mt][s * 4 + 3], b3, acc[mt], 0, 0, 0);
        }
    }

    // Epilogue: D col = ln -> n (wave window), row = lq*4+r -> m in m-tile mt
    float* pbase = part + (size_t)blockIdx.y * BATCH * OUT_F;
    const int n = n0 + (wave << 4) + ln;
    #pragma unroll
    for (int mt = 0; mt < 4; ++mt) {
        #pragma unroll
        for (int r = 0; r < 4; ++r) {
            const int m = mt * 16 + (lq << 2) + r;
            pbase[(size_t)m * OUT_F + n] = acc[mt][r];
        }
    }
}

extern "C" void kernel_launch(void* const* d_in, const int* in_sizes, int n_in,
                              void* d_out, int out_size, void* d_ws, size_t ws_size,
                              hipStream_t stream) {
    const float* x      = (const float*)d_in[0];
    const int*   qw     = (const int*)d_in[1];     // uint8 widened to int32 by harness
    const float* cw     = (const float*)d_in[2];
    const int*   cidx   = (const int*)d_in[3];
    const float* scales = (const float*)d_in[4];
    const float* bias   = (const float*)d_in[5];
    float*       out    = (float*)d_out;

    unsigned short* xp   = (unsigned short*)d_ws;                    // 512 KB
    float*          part = (float*)((char*)d_ws + (512 << 10));      // 16*64*11008*4 = 45 MB

    dim3 pgrid(IN_F / 256, BATCH);
    permute_x<<<pgrid, 256, 0, stream>>>(x, cidx, xp);
    qgemm<<<dim3(OUT_F / 64, KSPLIT), 256, 0, stream>>>(xp, qw, cw, scales, part);
    reduce_out<<<(BATCH * OUT_F / 4) / 256, 256, 0, stream>>>(part, bias, out);
}